// Round 3
// baseline (507.758 us; speedup 1.0000x reference)
//
#include <hip/hip_runtime.h>

#define MM 24
#define ROW_LEN 25
#define TPB 256

// Direct per-thread row processing. No LDS, no barriers, no waitcnt games.
// A wave's 7 loads cover one contiguous 6400 B region (64 rows x 100 B): every
// 64-B line is fully consumed, so HBM traffic is ideal; L1 absorbs the
// intra-wave granule sharing. TLP (8 waves/SIMD) hides HBM latency.
__global__ __launch_bounds__(TPB, 8)
void lpc_stab_kernel(const float* __restrict__ a, float* __restrict__ out, int B) {
    const long long row = (long long)blockIdx.x * TPB + threadIdx.x;
    if (row >= B) return;
    const float* gi = a + row * ROW_LEN;
    float*       go = out + row * ROW_LEN;

    // c[0] = gain K (pass-through). cc[0..23] = LPC coeffs, fully in registers.
    float c[ROW_LEN];

    // Load tail-first: step-down consumes c[24] first, c[1] last.
    c[24] = gi[24];
    #pragma unroll
    for (int i = 5; i >= 0; --i)
        *(float4*)(c + 4 * i) = *(const float4*)(gi + 4 * i);   // dword-aligned dwordx4

    float* cc = c + 1;

    // ---- step-down (LPC -> reflection). Clip folded in-place: after stage m,
    // slot cc[m-1] is dead for the recursion (only cc[0..m-2] are updated below m),
    // and step-up stage m reads exactly the clipped value from the same slot.
    // Recursion itself uses the UNCLIPPED km (matches reference: clip after full
    // step-down; BOUND == 1.0f in fp32).
    #pragma unroll
    for (int m = MM; m >= 1; --m) {
        const float km = cc[m - 1];
        cc[m - 1] = fminf(fmaxf(km, -1.0f), 1.0f);
        if (m >= 2) {
            const float inv = __builtin_amdgcn_rcpf(1.0f - km * km);
            #pragma unroll
            for (int i = 0; i < (m - 1) / 2; ++i) {
                const float x = cc[i], y = cc[m - 2 - i];
                cc[i]         = (x - km * y) * inv;
                cc[m - 2 - i] = (y - km * x) * inv;
            }
            if ((m - 1) & 1) {                       // middle element pairs with itself
                const int i = (m - 1) / 2;
                const float x = cc[i];
                cc[i] = (x - km * x) * inv;
            }
        }
    }

    // ---- step-up (reflection -> LPC), in place. cc[m-1] already holds clipped km.
    #pragma unroll
    for (int m = 1; m <= MM; ++m) {
        const float km = cc[m - 1];
        #pragma unroll
        for (int i = 0; i < (m - 1) / 2; ++i) {
            const float x = cc[i], y = cc[m - 2 - i];
            cc[i]         = x + km * y;
            cc[m - 2 - i] = y + km * x;
        }
        if ((m >= 2) && ((m - 1) & 1)) {
            const int i = (m - 1) / 2;
            cc[i] = cc[i] + km * cc[i];
        }
        // cc[m-1] = km;  // already there
    }

    // ---- store: 6x dwordx4 + 1 dword, same contiguous-region pattern as loads.
    #pragma unroll
    for (int i = 0; i < 6; ++i)
        *(float4*)(go + 4 * i) = *(const float4*)(c + 4 * i);
    go[24] = c[24];
}

extern "C" void kernel_launch(void* const* d_in, const int* in_sizes, int n_in,
                              void* d_out, int out_size, void* d_ws, size_t ws_size,
                              hipStream_t stream) {
    const float* a = (const float*)d_in[0];
    float* out = (float*)d_out;
    int B = in_sizes[0] / ROW_LEN;
    int blocks = (B + TPB - 1) / TPB;
    lpc_stab_kernel<<<blocks, TPB, 0, stream>>>(a, out, B);
}

// Round 4
// 348.595 us; speedup vs baseline: 1.4566x; 1.4566x over previous
//
#include <hip/hip_runtime.h>

#define MM 24
#define ROW_LEN 25
#define TPB 256
#define HALF_ROWS 128
#define HALF_V4 800                 // 128 rows * 25 floats / 4 = float4 per half-tile
#define TILE_V4 1600                // 256 rows per block tile
#define LDS_F (HALF_V4 * 4)         // 3200 floats = 12.8 KB -> 8 blocks/CU fits easily

__device__ __forceinline__ void gl_lds16(const float* g, float* l) {
    __builtin_amdgcn_global_load_lds((const __attribute__((address_space(1))) void*)g,
                                     (__attribute__((address_space(3))) void*)l,
                                     16, 0, 0);
}

// step-down -> clip (folded in-place) -> step-up, entirely in registers.
// Recursion uses UNCLIPPED km (reference clips after full step-down; BOUND==1.0f in fp32);
// slot cc[m-1] is dead for the recursion after stage m, so it safely holds the clipped km
// that step-up stage m later reads from the same slot.
__device__ __forceinline__ void lpc_row_regs(float* cc) {
    #pragma unroll
    for (int m = MM; m >= 1; --m) {
        const float km = cc[m - 1];
        cc[m - 1] = fminf(fmaxf(km, -1.0f), 1.0f);
        if (m >= 2) {
            const float inv = __builtin_amdgcn_rcpf(1.0f - km * km);
            #pragma unroll
            for (int i = 0; i < (m - 1) / 2; ++i) {
                const float x = cc[i], y = cc[m - 2 - i];
                cc[i]         = (x - km * y) * inv;
                cc[m - 2 - i] = (y - km * x) * inv;
            }
            if ((m - 1) & 1) {                     // middle element pairs with itself
                const int i = (m - 1) / 2;
                const float x = cc[i];
                cc[i] = (x - km * x) * inv;
            }
        }
    }
    #pragma unroll
    for (int m = 1; m <= MM; ++m) {
        const float km = cc[m - 1];                // clipped value already in place
        #pragma unroll
        for (int i = 0; i < (m - 1) / 2; ++i) {
            const float x = cc[i], y = cc[m - 2 - i];
            cc[i]         = x + km * y;
            cc[m - 2 - i] = y + km * x;
        }
        if ((m >= 2) && ((m - 1) & 1)) {
            const int i = (m - 1) / 2;
            cc[i] = cc[i] + km * cc[i];
        }
    }
}

__global__ __launch_bounds__(TPB, 8)     // force VGPR<=64 -> 8 waves/SIMD (100% occupancy)
void lpc_stab_kernel(const float* __restrict__ a, float* __restrict__ out, int B) {
    __shared__ float lds_f[LDS_F];
    const int tid  = threadIdx.x;
    const int wv   = tid >> 6;
    const int lane = tid & 63;
    const long long total4 = ((long long)B * ROW_LEN) >> 2;   // B*25 divisible by 4
    const long long base4  = (long long)blockIdx.x * TILE_V4;
    const float4* a4 = (const float4*)a;
    float4*       o4 = (float4*)out;
    const long long R = (long long)blockIdx.x * TPB + tid;    // this thread's global row
    const bool tail = (base4 + TILE_V4) > total4;             // only last block needs guards

    float K = 0.0f, c[MM];

    // ---------- stage half A (rows 0..127 of the tile), async global->LDS ----------
    #pragma unroll
    for (int it = 0; it < 4; ++it) {
        const int li = it * TPB + tid;                        // float4 index in half-tile
        if (li < HALF_V4) {
            float* lb = lds_f + 4 * (it * TPB + (tid & ~63)); // wave-uniform LDS base
            const long long g4 = base4 + li;
            if (!tail || g4 < total4) gl_lds16((const float*)(a4 + g4), lb);
        }
    }
    __syncthreads();                                          // vmcnt(0): half-A landed

    // ---------- read A: waves 0-1 pull their rows into registers ----------
    if (tid < HALF_ROWS && R < B) {
        const float* p = lds_f + tid * ROW_LEN;               // stride 25: conflict-free
        K = p[0];
        #pragma unroll
        for (int j = 0; j < MM; ++j) c[j] = p[j + 1];
    }
    __syncthreads();                                          // readers done before overwrite

    // ---------- stage half B (async) ----------
    #pragma unroll
    for (int it = 0; it < 4; ++it) {
        const int li = it * TPB + tid;
        if (li < HALF_V4) {
            float* lb = lds_f + 4 * (it * TPB + (tid & ~63));
            const long long g4 = base4 + HALF_V4 + li;
            if (!tail || g4 < total4) gl_lds16((const float*)(a4 + g4), lb);
        }
    }
    __builtin_amdgcn_sched_barrier(0);   // pin gl_lds issue BEFORE compute (overlap w/ flight)

    // ---------- compute A (overlaps half-B HBM flight) ----------
    if (tid < HALF_ROWS && R < B) lpc_row_regs(c);
    __syncthreads();                                          // vmcnt(0): half-B landed

    // ---------- read B: waves 2-3 pull their rows into registers ----------
    if (tid >= HALF_ROWS && R < B) {
        const float* p = lds_f + (tid - HALF_ROWS) * ROW_LEN;
        K = p[0];
        #pragma unroll
        for (int j = 0; j < MM; ++j) c[j] = p[j + 1];
    }
    __syncthreads();                                          // readers done before write-A

    if (tid < HALF_ROWS) {
        // ---------- write A + store A (same-wave DS ordering: no barrier needed) ----------
        if (R < B) {
            float* p = lds_f + tid * ROW_LEN;
            p[0] = K;
            #pragma unroll
            for (int j = 0; j < MM; ++j) p[j + 1] = c[j];
        }
        asm volatile("" ::: "memory");         // forbid compiler reordering ds_write vs ds_read
        const float4* l4 = (const float4*)lds_f;
        const int lb4 = wv * 400;              // wave stores exactly the rows IT wrote
        #pragma unroll
        for (int jj = 0; jj < 7; ++jj) {
            const int li = lb4 + jj * 64 + lane;
            if (jj * 64 + lane < 400) {
                const long long g4 = base4 + li;
                if (!tail || g4 < total4) o4[g4] = l4[li];
            }
        }
    } else {
        // ---------- compute B (overlaps waves 0-1's writeback/store) ----------
        if (R < B) lpc_row_regs(c);
    }
    __syncthreads();                           // store-A LDS reads done before write-B

    if (tid >= HALF_ROWS) {
        // ---------- write B + store B ----------
        if (R < B) {
            float* p = lds_f + (tid - HALF_ROWS) * ROW_LEN;
            p[0] = K;
            #pragma unroll
            for (int j = 0; j < MM; ++j) p[j + 1] = c[j];
        }
        asm volatile("" ::: "memory");
        const float4* l4 = (const float4*)lds_f;
        const int lb4 = (wv - 2) * 400;
        #pragma unroll
        for (int jj = 0; jj < 7; ++jj) {
            const int li = lb4 + jj * 64 + lane;
            if (jj * 64 + lane < 400) {
                const long long g4 = base4 + HALF_V4 + li;
                if (!tail || g4 < total4) o4[g4] = l4[li];
            }
        }
    }
}

extern "C" void kernel_launch(void* const* d_in, const int* in_sizes, int n_in,
                              void* d_out, int out_size, void* d_ws, size_t ws_size,
                              hipStream_t stream) {
    const float* a = (const float*)d_in[0];
    float* out = (float*)d_out;
    int B = in_sizes[0] / ROW_LEN;
    int blocks = (B + TPB - 1) / TPB;
    lpc_stab_kernel<<<blocks, TPB, 0, stream>>>(a, out, B);
}

// Round 5
// 333.943 us; speedup vs baseline: 1.5205x; 1.0439x over previous
//
#include <hip/hip_runtime.h>

#define MM 24
#define ROW_LEN 25
#define RPB 64                          // ONE wave per block: no s_barrier needed anywhere
#define TILE_F (RPB * ROW_LEN)          // 1600 floats = 6400 B per tile
#define BLOCKS_PER_CU 12                // 2 x 6.4 KB LDS -> 12 blocks/CU (LDS-capped)
#define MAX_BLOCKS (256 * BLOCKS_PER_CU)

// ---- async global -> LDS (no VGPR round-trip); size must be a literal ----
__device__ __forceinline__ void gl_lds16(const float* g, float* l) {
    __builtin_amdgcn_global_load_lds((const __attribute__((address_space(1))) void*)g,
                                     (__attribute__((address_space(3))) void*)l,
                                     16, 0, 0);
}
__device__ __forceinline__ void gl_lds4(const float* g, float* l) {
    __builtin_amdgcn_global_load_lds((const __attribute__((address_space(1))) void*)g,
                                     (__attribute__((address_space(3))) void*)l,
                                     4, 0, 0);
}

// counted vmcnt; "memory" clobber stops the compiler moving ds/global ops across it
#define WAIT_VM(N) asm volatile("s_waitcnt vmcnt(" #N ")" ::: "memory")

// stage one 6400 B tile: 6 x (64 lanes x 16 B) + 1 x (64 lanes x 4 B) = 7 VMEM ops
__device__ __forceinline__ void stage_tile(const float* __restrict__ a, float* buf,
                                           long long tile, int lane) {
    const float* g = a + tile * (long long)TILE_F;
    #pragma unroll
    for (int i = 0; i < 6; ++i)
        gl_lds16(g + i * 256 + lane * 4, buf + i * 256);   // lds dst: uniform base + lane*16
    gl_lds4(g + 1536 + lane, buf + 1536);
}

// LDS tile -> regs -> coalesced global store (7 VMEM ops). The compiler inserts
// lgkmcnt waits for the ds_read results before the dependent global_stores, which
// also transitively orders LDS-buffer reuse vs. the NEXT iteration's gl_lds.
__device__ __forceinline__ void store_tile(float* __restrict__ outp, const float* buf,
                                           long long tile, int lane) {
    float4 r[6];
    #pragma unroll
    for (int i = 0; i < 6; ++i)
        r[i] = *(const float4*)(buf + i * 256 + lane * 4); // linear b128, conflict-free
    float rt = buf[1536 + lane];
    float* g = outp + tile * (long long)TILE_F;
    #pragma unroll
    for (int i = 0; i < 6; ++i)
        *(float4*)(g + i * 256 + lane * 4) = r[i];
    g[1536 + lane] = rt;
}

// step-down -> clip (folded in-place) -> step-up on one LDS row (stride 25:
// gcd(25,32)=1, conflict-free). p[0] (gain K) passes through LDS untouched.
// Recursion uses UNCLIPPED km (reference clips after full step-down; BOUND==1.0f
// in fp32); slot cc[m-1] is dead for the recursion after stage m, so it holds the
// clipped km that step-up stage m later reads from the same slot.
__device__ __forceinline__ void lpc_row(float* p) {
    float cc[MM];
    #pragma unroll
    for (int j = 0; j < MM; ++j) cc[j] = p[j + 1];

    #pragma unroll
    for (int m = MM; m >= 1; --m) {
        const float km = cc[m - 1];
        cc[m - 1] = fminf(fmaxf(km, -1.0f), 1.0f);
        if (m >= 2) {
            const float inv = __builtin_amdgcn_rcpf(1.0f - km * km);
            #pragma unroll
            for (int i = 0; i < (m - 1) / 2; ++i) {
                const float x = cc[i], y = cc[m - 2 - i];
                cc[i]         = (x - km * y) * inv;
                cc[m - 2 - i] = (y - km * x) * inv;
            }
            if ((m - 1) & 1) {                     // middle element pairs with itself
                const int i = (m - 1) / 2;
                const float x = cc[i];
                cc[i] = (x - km * x) * inv;
            }
        }
    }
    #pragma unroll
    for (int m = 1; m <= MM; ++m) {
        const float km = cc[m - 1];                // clipped value already in place
        #pragma unroll
        for (int i = 0; i < (m - 1) / 2; ++i) {
            const float x = cc[i], y = cc[m - 2 - i];
            cc[i]         = x + km * y;
            cc[m - 2 - i] = y + km * x;
        }
        if ((m >= 2) && ((m - 1) & 1)) {
            const int i = (m - 1) / 2;
            cc[i] = cc[i] + km * cc[i];
        }
    }
    #pragma unroll
    for (int j = 0; j < MM; ++j) p[j + 1] = cc[j];
}

__global__ __launch_bounds__(RPB, 3)    // 3 waves/SIMD floor; VGPR ~40, no pressure
void lpc_stab_kernel(const float* __restrict__ a, float* __restrict__ out,
                     long long ntiles, int rem) {
    __shared__ float bufA[TILE_F];
    __shared__ float bufB[TILE_F];
    const int lane = threadIdx.x;
    const long long gstride = gridDim.x;
    long long t = blockIdx.x;

    if (t < ntiles) {
        // ---- prologue: 1-deep prefetch, counted wait ----
        stage_tile(a, bufA, t, lane);                      // L(t0): 7 vmem
        float* cur = bufA;
        float* nxt = bufB;
        long long t1 = t + gstride;
        if (t1 < ntiles) {
            stage_tile(a, bufB, t1, lane);                 // L(t1): 7 vmem
            WAIT_VM(7);                                    // L(t0) landed; L(t1) in flight
        } else {
            WAIT_VM(0);
        }
        lpc_row(cur + lane * ROW_LEN);
        store_tile(out, cur, t, lane);                     // S(t0): 7 vmem
        t = t1;
        { float* tmp = cur; cur = nxt; nxt = tmp; }

        // ---- steady state: NO barriers. [L(t)|S(t-1)|L(t+1)] outstanding,
        //      wait vmcnt(14): L(t) landed, S(t-1)+L(t+1) stay in flight. ----
        while (t < ntiles) {
            const long long tn = t + gstride;
            if (tn < ntiles) {
                stage_tile(a, nxt, tn, lane);              // issue next-tile loads FIRST
                WAIT_VM(14);
            } else {
                WAIT_VM(7);                                // leaves S(t-1); L(t) landed
            }
            lpc_row(cur + lane * ROW_LEN);
            store_tile(out, cur, t, lane);
            t = tn;
            float* tmp = cur; cur = nxt; nxt = tmp;
        }
    }

    // ---- tail rows (B % 64 — zero for this shape): direct global, no LDS ----
    if (rem && blockIdx.x == 0 && lane < rem) {
        const long long r0 = ntiles * RPB + lane;
        const float* gi = a + r0 * ROW_LEN;
        float*       go = out + r0 * ROW_LEN;
        float row[ROW_LEN];
        #pragma unroll
        for (int j = 0; j < ROW_LEN; ++j) row[j] = gi[j];
        lpc_row(row);                                      // operates on row[1..24]
        #pragma unroll
        for (int j = 0; j < ROW_LEN; ++j) go[j] = row[j];
    }
}

extern "C" void kernel_launch(void* const* d_in, const int* in_sizes, int n_in,
                              void* d_out, int out_size, void* d_ws, size_t ws_size,
                              hipStream_t stream) {
    const float* a = (const float*)d_in[0];
    float* out = (float*)d_out;
    long long B = (long long)in_sizes[0] / ROW_LEN;
    long long ntiles = B / RPB;
    int rem = (int)(B % RPB);
    long long want = ntiles > 0 ? ntiles : 1;
    int blocks = (int)(want < MAX_BLOCKS ? want : MAX_BLOCKS);
    lpc_stab_kernel<<<blocks, RPB, 0, stream>>>(a, out, ntiles, rem);
}